// Round 1
// baseline (376.805 us; speedup 1.0000x reference)
//
#include <hip/hip_runtime.h>

#define NB 32
#define ND 64
#define NT 4096
#define NK 512
#define NN (NB*NT)

// ---------------------------------------------------------------------------
// enorm[k] = numpy-pairwise sum of codebook[k,:]^2  (n=64 -> 8-accumulator
// pattern, square rounded before add; no FMA contraction).
// ---------------------------------------------------------------------------
__global__ void enorm_kernel(const float* __restrict__ cb, float* __restrict__ enorm) {
    int k = blockIdx.x * blockDim.x + threadIdx.x;
    if (k >= NK) return;
    const float* e = cb + (size_t)k * ND;
    float r[8];
#pragma unroll
    for (int j = 0; j < 8; ++j) {
        float s = __fmul_rn(e[j], e[j]);
#pragma unroll
        for (int i = 1; i < 8; ++i) {
            float p = __fmul_rn(e[8 * i + j], e[8 * i + j]);
            s = __fadd_rn(s, p);
        }
        r[j] = s;
    }
    float res = __fadd_rn(__fadd_rn(__fadd_rn(r[0], r[1]), __fadd_rn(r[2], r[3])),
                          __fadd_rn(__fadd_rn(r[4], r[5]), __fadd_rn(r[6], r[7])));
    enorm[k] = res;
}

// ---------------------------------------------------------------------------
// Main kernel: one thread per row n=(b,t). lane = t (coalesced z access).
// dist_k = round(round(znorm + enorm_k) - 2*dot_k), dot_k = ascending fmaf
// chain (BLAS-sgemm-style). argmin = first strict min (numpy argmin).
// ---------------------------------------------------------------------------
__global__ __launch_bounds__(256) void vq_main(const float* __restrict__ z,
                                               const float* __restrict__ cb,
                                               const float* __restrict__ enorm,
                                               float* __restrict__ qout,
                                               float* __restrict__ idxout,
                                               double* __restrict__ loss_acc) {
    const int bi  = blockIdx.x;
    const int b   = bi >> 4;                       // 32 b's x 16 t-tiles
    const int t   = ((bi & 15) << 8) + threadIdx.x;

    const float* zp = z + (size_t)b * ND * NT + t; // stride NT per d
    float zv[ND];
#pragma unroll
    for (int d = 0; d < ND; ++d) zv[d] = zp[(size_t)d * NT];

    // znorm: numpy pairwise pattern (rounded squares, sequential 8-acc)
    float r[8];
#pragma unroll
    for (int j = 0; j < 8; ++j) {
        float s = __fmul_rn(zv[j], zv[j]);
#pragma unroll
        for (int i = 1; i < 8; ++i) {
            float p = __fmul_rn(zv[8 * i + j], zv[8 * i + j]);
            s = __fadd_rn(s, p);
        }
        r[j] = s;
    }
    const float zn = __fadd_rn(__fadd_rn(__fadd_rn(r[0], r[1]), __fadd_rn(r[2], r[3])),
                               __fadd_rn(__fadd_rn(r[4], r[5]), __fadd_rn(r[6], r[7])));

    float best = __builtin_inff();
    int   bidx = 0;

    for (int k = 0; k < NK; k += 4) {
        const float* e0 = cb + (size_t)(k + 0) * ND;
        const float* e1 = cb + (size_t)(k + 1) * ND;
        const float* e2 = cb + (size_t)(k + 2) * ND;
        const float* e3 = cb + (size_t)(k + 3) * ND;
        float a0 = 0.0f, a1 = 0.0f, a2 = 0.0f, a3 = 0.0f;
#pragma unroll
        for (int d = 0; d < ND; ++d) {
            const float zd = zv[d];
            a0 = __builtin_fmaf(zd, e0[d], a0);
            a1 = __builtin_fmaf(zd, e1[d], a1);
            a2 = __builtin_fmaf(zd, e2[d], a2);
            a3 = __builtin_fmaf(zd, e3[d], a3);
        }
        const float D0 = __fsub_rn(__fadd_rn(zn, enorm[k + 0]), __fmul_rn(2.0f, a0));
        const float D1 = __fsub_rn(__fadd_rn(zn, enorm[k + 1]), __fmul_rn(2.0f, a1));
        const float D2 = __fsub_rn(__fadd_rn(zn, enorm[k + 2]), __fmul_rn(2.0f, a2));
        const float D3 = __fsub_rn(__fadd_rn(zn, enorm[k + 3]), __fmul_rn(2.0f, a3));
        if (D0 < best) { best = D0; bidx = k + 0; }
        if (D1 < best) { best = D1; bidx = k + 1; }
        if (D2 < best) { best = D2; bidx = k + 2; }
        if (D3 < best) { best = D3; bidx = k + 3; }
    }

    // Epilogue: straight-through output (bit-replicates zt + (q - zt)),
    // loss partial, index.
    const float* e = cb + (size_t)bidx * ND;
    float* qp = qout + (size_t)b * ND * NT + t;
    double lsum = 0.0;
#pragma unroll
    for (int d = 0; d < ND; ++d) {
        const float diff = __fsub_rn(e[d], zv[d]);   // quantized - zt
        const float qs   = __fadd_rn(zv[d], diff);   // zt + (q - zt)
        qp[(size_t)d * NT] = qs;
        lsum += (double)diff * (double)diff;
    }
    idxout[(size_t)b * NT + t] = (float)bidx;

    // block reduce lsum -> one atomic per block
#pragma unroll
    for (int off = 32; off > 0; off >>= 1) lsum += __shfl_down(lsum, off, 64);
    __shared__ double sred[4];
    const int tid = threadIdx.x;
    if ((tid & 63) == 0) sred[tid >> 6] = lsum;
    __syncthreads();
    if (tid == 0) {
        double s = (sred[0] + sred[1]) + (sred[2] + sred[3]);
        atomicAdd(loss_acc, s);
    }
}

__global__ void finalize_kernel(const double* __restrict__ loss_acc,
                                float* __restrict__ out0) {
    // vq_loss = m + 0.25*m = 1.25*m,  m = sum / (B*T*D)
    double m = loss_acc[0] / (double)((size_t)NB * NT * ND);
    out0[0] = (float)(1.25 * m);
}

extern "C" void kernel_launch(void* const* d_in, const int* in_sizes, int n_in,
                              void* d_out, int out_size, void* d_ws, size_t ws_size,
                              hipStream_t stream) {
    const float* z  = (const float*)d_in[0];
    const float* cb = (const float*)d_in[1];

    float* out      = (float*)d_out;
    float* loss_out = out;                                  // 1 elem
    float* qout     = out + 1;                              // B*D*T elems
    float* idxout   = out + 1 + (size_t)NB * ND * NT;       // B*T elems

    double* loss_acc = (double*)d_ws;
    float*  enorm    = (float*)((char*)d_ws + 16);

    hipMemsetAsync(d_ws, 0, 16, stream);
    enorm_kernel<<<1, 512, 0, stream>>>(cb, enorm);
    vq_main<<<512, 256, 0, stream>>>(z, cb, enorm, qout, idxout, loss_acc);
    finalize_kernel<<<1, 1, 0, stream>>>(loss_acc, loss_out);
}